// Round 1
// baseline (235.932 us; speedup 1.0000x reference)
//
#include <hip/hip_runtime.h>

// SparseMCFModel — the output `flow` depends ONLY on demands, edge_row, edge_col.
// Proof: w = seg_softmax(pred_w[edge_row], edge_row, n) has identical logits
// within each segment (logit for edge e is pred_w[row_e]; segment id is row_e),
// so w_e = 1/deg(row_e) exactly. The GAT/GRU/decoder never influence the output.
//
// Flow recurrence in node space:
//   q1[v]   = relu(demands[v])
//   qt[v]   = relu(demands[v]) + sum_{e: col_e = v} w_e * q_{t-1}[row_e]   (t = 2..10)
//   flow[e] = w_e * q10[row_e]

#define N_NODES 20000
#define N_EDGES 200000
#define FLOW_ITERS 10

__global__ void k_hist(const int* __restrict__ row, int* __restrict__ deg) {
    int e = blockIdx.x * blockDim.x + threadIdx.x;
    if (e < N_EDGES) atomicAdd(&deg[row[e]], 1);
}

__global__ void k_w(const int* __restrict__ row, const int* __restrict__ deg,
                    float* __restrict__ w) {
    int e = blockIdx.x * blockDim.x + threadIdx.x;
    if (e < N_EDGES) w[e] = 1.0f / (float)deg[row[e]];
}

__global__ void k_init_q(const float* __restrict__ demands, float* __restrict__ q) {
    int v = blockIdx.x * blockDim.x + threadIdx.x;
    if (v < N_NODES) q[v] = fmaxf(demands[v], 0.0f);
}

__global__ void k_scatter(const int* __restrict__ row, const int* __restrict__ col,
                          const float* __restrict__ w, const float* __restrict__ qprev,
                          float* __restrict__ qnew) {
    int e = blockIdx.x * blockDim.x + threadIdx.x;
    if (e < N_EDGES) {
        float f = w[e] * qprev[row[e]];
        atomicAdd(&qnew[col[e]], f);
    }
}

__global__ void k_flow(const int* __restrict__ row, const float* __restrict__ w,
                       const float* __restrict__ q, float* __restrict__ out) {
    int e = blockIdx.x * blockDim.x + threadIdx.x;
    if (e < N_EDGES) out[e] = w[e] * q[row[e]];
}

extern "C" void kernel_launch(void* const* d_in, const int* in_sizes, int n_in,
                              void* d_out, int out_size, void* d_ws, size_t ws_size,
                              hipStream_t stream) {
    const float* demands  = (const float*)d_in[1];   // [N,1]
    const int*   edge_row = (const int*)d_in[2];     // [E]
    const int*   edge_col = (const int*)d_in[3];     // [E]
    float*       out      = (float*)d_out;           // [E]

    // workspace layout
    char* ws = (char*)d_ws;
    int*   deg = (int*)ws;                                  ws += N_NODES * sizeof(int);
    float* w   = (float*)ws;                                ws += N_EDGES * sizeof(float);
    float* q0  = (float*)ws;                                ws += N_NODES * sizeof(float);
    float* q1  = (float*)ws;

    const int BE = 256, GE = (N_EDGES + BE - 1) / BE;
    const int BN = 256, GN = (N_NODES + BN - 1) / BN;

    // deg histogram -> w = 1/deg[row]
    hipMemsetAsync(deg, 0, N_NODES * sizeof(int), stream);
    k_hist<<<GE, BE, 0, stream>>>(edge_row, deg);
    k_w<<<GE, BE, 0, stream>>>(edge_row, deg, w);

    // q1 = relu(demands)
    float* qc = q0;
    float* qn = q1;
    k_init_q<<<GN, BN, 0, stream>>>(demands, qc);

    // q_t for t = 2..FLOW_ITERS
    for (int t = 2; t <= FLOW_ITERS; ++t) {
        k_init_q<<<GN, BN, 0, stream>>>(demands, qn);
        k_scatter<<<GE, BE, 0, stream>>>(edge_row, edge_col, w, qc, qn);
        float* tmp = qc; qc = qn; qn = tmp;
    }

    // flow = w * q10[row]
    k_flow<<<GE, BE, 0, stream>>>(edge_row, w, qc, out);
}